// Round 5
// baseline (216.326 us; speedup 1.0000x reference)
//
#include <hip/hip_runtime.h>
#include <stdint.h>

typedef __attribute__((ext_vector_type(8)))  short  short8;
typedef __attribute__((ext_vector_type(8)))  __bf16 bf16x8;
typedef __attribute__((ext_vector_type(16))) float  floatx16;
typedef __attribute__((ext_vector_type(4)))  float  floatx4;
typedef __attribute__((ext_vector_type(2)))  float  float2v;
typedef __attribute__((ext_vector_type(4)))  uint32_t uint4v;

union Frag { short8 s; bf16x8 v; uint4v d; };
union FU   { float f; uint32_t u; };

// round-to-nearest-even f32 -> bf16 (setup only)
__device__ __forceinline__ short f2bf(float f) {
    FU x; x.f = f;
    uint32_t r = x.u + 0x7fffu + ((x.u >> 16) & 1u);
    return (short)(r >> 16);
}

// pack two f32 -> bf16x2 dword, round-half-up: 2 adds + 1 v_perm
__device__ __forceinline__ uint32_t pack_bf2(float lo, float hi) {
    FU a, b; a.f = lo; b.f = hi;
    return __builtin_amdgcn_perm(b.u + 0x8000u, a.u + 0x8000u, 0x07060302u);
}

__device__ __forceinline__ float fexp2(float x) { return __builtin_amdgcn_exp2f(x); }
__device__ __forceinline__ float frcp(float x)  { return __builtin_amdgcn_rcpf(x); }

// T = exp2(min(arg,15)) + 1 for the pair (acc[j], acc[j+8]).
// No lower clamp: exp2 underflow -> 0 -> T=1 is the exact limit.
// Upper clamp 15 keeps the 8-way product <= 2^121 (no overflow);
// tanh error at the clamp ~6e-5, far under tolerance.
__device__ __forceinline__ float2v tpair(float a, float b) {
    float2v t;
    t.x = fexp2(fminf(a, 15.0f));
    t.y = fexp2(fminf(b, 15.0f));
    return t + 1.0f;
}

struct NTab { floatx4 q; };

// one half (32 nodes) tanh-sum given the MFMA acc and the shared N quads
__device__ __forceinline__ float half_tanh(
    const floatx16& acc,
    const floatx4& NQ0, const floatx4& NQ1,
    const floatx4& NQ2, const floatx4& NQ3)
{
    union { floatx4 q; float2v p[2]; } N0, N1, N2, N3;
    N0.q = NQ0; N1.q = NQ1; N2.q = NQ2; N3.q = NQ3;

    float2v T0 = tpair(acc[0], acc[8]);
    float2v T1 = tpair(acc[1], acc[9]);
    float2v P01 = T0 * T1;
    float2v n01 = N0.p[0] * T1 + N0.p[1] * T0;
    float2v T2 = tpair(acc[2], acc[10]);
    float2v T3 = tpair(acc[3], acc[11]);
    float2v P23 = T2 * T3;
    float2v n23 = N1.p[0] * T3 + N1.p[1] * T2;
    float2v T4 = tpair(acc[4], acc[12]);
    float2v T5 = tpair(acc[5], acc[13]);
    float2v P45 = T4 * T5;
    float2v n45 = N2.p[0] * T5 + N2.p[1] * T4;
    float2v T6 = tpair(acc[6], acc[14]);
    float2v T7 = tpair(acc[7], acc[15]);
    float2v P67 = T6 * T7;
    float2v n67 = N3.p[0] * T7 + N3.p[1] * T6;

    float2v PA = P01 * P23, PB = P45 * P67;
    float2v nA = n01 * P23 + n23 * P01;
    float2v nB = n45 * P67 + n67 * P45;
    float2v P  = PA * PB;
    float2v Num = nA * PB + nB * PA;
    float2v R; R.x = frcp(P.x); R.y = frcp(P.y);
    float2v Yh = Num * R;
    return Yh.x + Yh.y;
}

// one pipeline step for slot S: consume the tile PAIR (t, t+1) held in
// zb[S], refill zb[S] with the pair 2 steps ahead, compute both tiles as
// two independent instruction streams (compiler interleaves), store, t+=W2.
template<int S>
__device__ __forceinline__ void pair_step(
    floatx4 (&zb)[2][4], int& t, int W2, int tlast, const float* zp,
    const Frag (&af)[2], const floatx4* cqg, const floatx4* nqg,
    float base, float* __restrict__ out, int m, int g)
{
    Frag bA, bB;   // consuming zb[S] waits only on its own pair; the other
    bA.d[0] = pack_bf2(zb[S][0].x, zb[S][0].y);   // slot stays in flight
    bA.d[1] = pack_bf2(zb[S][0].z, zb[S][0].w);
    bA.d[2] = pack_bf2(zb[S][1].x, zb[S][1].y);
    bA.d[3] = pack_bf2(zb[S][1].z, zb[S][1].w);
    bB.d[0] = pack_bf2(zb[S][2].x, zb[S][2].y);
    bB.d[1] = pack_bf2(zb[S][2].z, zb[S][2].w);
    bB.d[2] = pack_bf2(zb[S][3].x, zb[S][3].y);
    bB.d[3] = pack_bf2(zb[S][3].z, zb[S][3].w);

    {   // refill: keeps ~4KB outstanding per wave at all times
        int ta = t + 2 * W2; if (ta > tlast) ta = tlast;   // benign dup
        int tb = ta + 1;     if (tb > tlast) tb = tlast;
        const float* qa = zp + (size_t)ta * 512;
        const float* qb = zp + (size_t)tb * 512;
        zb[S][0] = *(const floatx4*)qa;
        zb[S][1] = *(const floatx4*)(qa + 4);
        zb[S][2] = *(const floatx4*)qb;
        zb[S][3] = *(const floatx4*)(qb + 4);
    }

    // laundered per-step index: fresh LDS broadcast reads (shared by the
    // pair) so constant tables never become resident VGPRs
    int zz = 0;
    asm volatile("" : "+v"(zz));
    const floatx4* cq = cqg + zz;
    const floatx4* nq = nqg + zz;

    float yA = 0.0f, yB = 0.0f;
    #pragma unroll
    for (int h = 0; h < 2; ++h) {
        union { floatx16 v; floatx4 q[4]; } C;
        C.q[0] = cq[h * 4 + 0]; C.q[1] = cq[h * 4 + 1];
        C.q[2] = cq[h * 4 + 2]; C.q[3] = cq[h * 4 + 3];
        // two independent MFMAs (same A, same C, different B)
        floatx16 aA = __builtin_amdgcn_mfma_f32_32x32x16_bf16(
            af[h].v, bA.v, C.v, 0, 0, 0);
        floatx16 aB = __builtin_amdgcn_mfma_f32_32x32x16_bf16(
            af[h].v, bB.v, C.v, 0, 0, 0);

        floatx4 NQ0 = nq[h * 4 + 0], NQ1 = nq[h * 4 + 1];
        floatx4 NQ2 = nq[h * 4 + 2], NQ3 = nq[h * 4 + 3];

        // two independent tanh trees; compiler interleaves them
        yA += half_tanh(aA, NQ0, NQ1, NQ2, NQ3);
        yB += half_tanh(aB, NQ0, NQ1, NQ2, NQ3);
    }

    float oA = __shfl_xor(yA, 32, 64);
    float oB = __shfl_xor(yB, 32, 64);
    if (g == 0) {
        int tb = t + 1; if (tb > tlast) tb = tlast;  // dup store: same value
        out[(size_t)t  * 32 + m] = base + yA + oA;
        out[(size_t)tb * 32 + m] = base + yB + oB;
    }
    t += W2;
}

// y[b] = a0 + sum_k bk[k] * tanh(ck[k,:].z[b,:] + dk[k])
//
// D = mfma_32x32x16_bf16(A=s*ck, B=z, C=s*dk) -> D[node][row] = s*(dot+dk),
// s = 2*log2(e); col(lane&31)=batch row, node=(reg&3)+8*(reg>>2)+4*(lane>>5).
// tanh(t) = 1 - 2/(exp2(s*t)+1); 8-way shared denominator per half.
//
// R14 (two fixes on R13):
//  1. BUG: R13 launched 2048 persistent blocks with a 6-block/CU residency
//     cap -> 25% of tiles ran as a low-occupancy serial tail after the
//     resident blocks completed. Now __launch_bounds__(256,5) and
//     blocks <= 1280 = 5/CU: the whole grid is co-resident from t=0.
//  2. ILP: every prior version computed ONE tile's MFMA->exp2-tree->rcp
//     chain serially per wave (R0 counters: ~985 issue-cy/tile vs ~450
//     static -> 2x stall-stretch, avg occupancy never filled the holes).
//     Each step now runs TWO independent tiles back-to-back in one
//     unrolled region -> 2 chains/wave, 10 streams/SIMD; C/N table reads
//     shared by the pair (halves per-tile LDS ops).
//  Depth-2 pair pipeline (4KB/wave outstanding), preamble ~once/13 tiles.
__global__ __launch_bounds__(256, 5) void mave_kernel(
    const float* __restrict__ z,
    const float* __restrict__ a0,
    const float* __restrict__ bk,
    const float* __restrict__ ck,
    const float* __restrict__ dk,
    float* __restrict__ out,
    int ntiles)
{
    const int lane = threadIdx.x & 63;
    const int m    = lane & 31;
    const int g    = lane >> 5;
    const int widx = threadIdx.x >> 6;
    const float S  = 2.885390081777927f;  // 2*log2(e)

    // per-WAVE table copies: no cross-wave sharing -> no __syncthreads
    __shared__ __align__(16) float   cinitL[4][2][2][16];  // [wave][g][h][reg]
    __shared__ __align__(16) float2v nbL[4][2][2][8];      // [wave][g][h][j]

    const int W   = (int)(gridDim.x << 2);   // total waves
    const int W2  = W * 2;                   // tiles per step (pairs)
    const int wid = (int)(blockIdx.x * 4 + widx);
    const int t0  = wid * 2;
    if (t0 >= ntiles) return;
    const int tlast = ntiles - 1;
    const int iters = (tlast - t0) / W2 + 1;

    // ---- loads, oldest first: ck (A fragments) ----
    const float* c0 = ck + m * 16 + g * 8;
    floatx4 ckv0 = *(const floatx4*)c0;
    floatx4 ckv1 = *(const floatx4*)(c0 + 4);
    floatx4 ckv2 = *(const floatx4*)(c0 + 512);
    floatx4 ckv3 = *(const floatx4*)(c0 + 516);

    // ---- table sources (per-lane gathers; tiny, L1/L2-hot) ----
    const int tl = lane;
    const int gg = tl >> 5, hh = (tl >> 4) & 1, rr = tl & 15;
    const int nc = (rr & 3) + 8 * (rr >> 2) + 4 * gg + 32 * hh;
    float dkv = dk[nc];
    float bkt = bk[tl];
    const int g2 = tl >> 4, h2 = (tl >> 3) & 1, j2 = tl & 7;
    const int nl = (j2 & 3) + 8 * (j2 >> 2) + 4 * g2 + 32 * h2;
    float bnl = 0.0f, bnh = 0.0f;
    if (tl < 32) { bnl = bk[nl]; bnh = bk[nl + 16]; }   // exec-masked
    float a0v = a0[0];

    // ---- z pipeline: 2 slots, each a tile PAIR (youngest loads) ----
    const float* zp = z + (size_t)m * 16 + g * 8;
    floatx4 zb[2][4];
    #pragma unroll
    for (int s = 0; s < 2; ++s) {
        int ta = t0 + s * W2; if (ta > tlast) ta = tlast;   // benign dup
        int tb = ta + 1;      if (tb > tlast) tb = tlast;
        const float* qa = zp + (size_t)ta * 512;
        const float* qb = zp + (size_t)tb * 512;
        zb[s][0] = *(const floatx4*)qa;
        zb[s][1] = *(const floatx4*)(qa + 4);
        zb[s][2] = *(const floatx4*)qb;
        zb[s][3] = *(const floatx4*)(qb + 4);
    }

    // ---- consume ck (wait covers only ck; z stays in flight) ----
    Frag af[2];
    #pragma unroll
    for (int e = 0; e < 4; ++e) {
        af[0].s[e]     = f2bf(ckv0[e] * S);
        af[0].s[e + 4] = f2bf(ckv1[e] * S);
        af[1].s[e]     = f2bf(ckv2[e] * S);
        af[1].s[e + 4] = f2bf(ckv3[e] * S);
    }

    // ---- per-wave tables; same-wave RAW ordered by lgkmcnt only ----
    cinitL[widx][gg][hh][rr] = S * dkv;
    if (tl < 32) {
        float2v nb; nb.x = -2.0f * bnl; nb.y = -2.0f * bnh;
        nbL[widx][g2][h2][j2] = nb;
    }
    float bv = bkt;
    #pragma unroll
    for (int d = 1; d < 64; d <<= 1) bv += __shfl_xor(bv, d, 64);
    const float base = a0v + bv;   // all lanes hold it

    const floatx4* cqg = (const floatx4*)&cinitL[widx][g][0][0];  // 8 quads
    const floatx4* nqg = (const floatx4*)&nbL[widx][g][0][0];     // 8 quads

    // ---- persistent rolling loop: 2 tiles/step, slots alternate ----
    int t   = t0;
    int rem = iters;
    for (;;) {
        pair_step<0>(zb, t, W2, tlast, zp, af, cqg, nqg, base, out, m, g);
        if (--rem == 0) break;
        pair_step<1>(zb, t, W2, tlast, zp, af, cqg, nqg, base, out, m, g);
        if (--rem == 0) break;
    }
}

extern "C" void kernel_launch(void* const* d_in, const int* in_sizes, int n_in,
                              void* d_out, int out_size, void* d_ws, size_t ws_size,
                              hipStream_t stream) {
    const float* z  = (const float*)d_in[0];
    const float* a0 = (const float*)d_in[1];
    const float* bk = (const float*)d_in[2];
    const float* ck = (const float*)d_in[3];
    const float* dk = (const float*)d_in[4];
    float* out = (float*)d_out;

    const int B      = in_sizes[0] / 16;       // z is [B,16]
    const int ntiles = B / 32;                 // 32 batch rows per wave-tile

    // persistent, residency-exact: 5 blocks/CU * 256 CU = 1280 blocks
    // (4 waves each, 2 tiles/step); whole grid co-resident, no launch tail
    int blocks = (ntiles + 7) / 8;
    if (blocks > 1280) blocks = 1280;
    hipLaunchKernelGGL(mave_kernel, dim3(blocks), dim3(256), 0, stream,
                       z, a0, bk, ck, dk, out, ntiles);
}

// Round 6
// 202.442 us; speedup vs baseline: 1.0686x; 1.0686x over previous
//
#include <hip/hip_runtime.h>
#include <stdint.h>

typedef __attribute__((ext_vector_type(8)))  short  short8;
typedef __attribute__((ext_vector_type(8)))  __bf16 bf16x8;
typedef __attribute__((ext_vector_type(16))) float  floatx16;
typedef __attribute__((ext_vector_type(4)))  float  floatx4;
typedef __attribute__((ext_vector_type(2)))  float  float2v;
typedef __attribute__((ext_vector_type(4)))  uint32_t uint4v;

union Frag { short8 s; bf16x8 v; uint4v d; };
union FU   { float f; uint32_t u; };

// round-to-nearest-even f32 -> bf16 (setup only)
__device__ __forceinline__ short f2bf(float f) {
    FU x; x.f = f;
    uint32_t r = x.u + 0x7fffu + ((x.u >> 16) & 1u);
    return (short)(r >> 16);
}

// pack two f32 -> bf16x2 dword, round-half-up: 2 adds + 1 v_perm
__device__ __forceinline__ uint32_t pack_bf2(float lo, float hi) {
    FU a, b; a.f = lo; b.f = hi;
    return __builtin_amdgcn_perm(b.u + 0x8000u, a.u + 0x8000u, 0x07060302u);
}

__device__ __forceinline__ float fexp2(float x) { return __builtin_amdgcn_exp2f(x); }
__device__ __forceinline__ float frcp(float x)  { return __builtin_amdgcn_rcpf(x); }

// T = exp2(min(arg,15)) + 1 for the pair (acc[j], acc[j+8]).
// No lower clamp: exp2 underflow -> 0 -> T=1 is the exact limit.
// Upper clamp 15 keeps the 8-way product <= 2^121 (no overflow);
// tanh error at the clamp ~6e-5, far under tolerance.
__device__ __forceinline__ float2v tpair(float a, float b) {
    float2v t;
    t.x = fexp2(fminf(a, 15.0f));
    t.y = fexp2(fminf(b, 15.0f));
    return t + 1.0f;
}

// one half (32 nodes) tanh-sum given the MFMA acc and the shared N quads
__device__ __forceinline__ float half_tanh(
    const floatx16& acc,
    const floatx4& NQ0, const floatx4& NQ1,
    const floatx4& NQ2, const floatx4& NQ3)
{
    union { floatx4 q; float2v p[2]; } N0, N1, N2, N3;
    N0.q = NQ0; N1.q = NQ1; N2.q = NQ2; N3.q = NQ3;

    float2v T0 = tpair(acc[0], acc[8]);
    float2v T1 = tpair(acc[1], acc[9]);
    float2v P01 = T0 * T1;
    float2v n01 = N0.p[0] * T1 + N0.p[1] * T0;
    float2v T2 = tpair(acc[2], acc[10]);
    float2v T3 = tpair(acc[3], acc[11]);
    float2v P23 = T2 * T3;
    float2v n23 = N1.p[0] * T3 + N1.p[1] * T2;
    float2v T4 = tpair(acc[4], acc[12]);
    float2v T5 = tpair(acc[5], acc[13]);
    float2v P45 = T4 * T5;
    float2v n45 = N2.p[0] * T5 + N2.p[1] * T4;
    float2v T6 = tpair(acc[6], acc[14]);
    float2v T7 = tpair(acc[7], acc[15]);
    float2v P67 = T6 * T7;
    float2v n67 = N3.p[0] * T7 + N3.p[1] * T6;

    float2v PA = P01 * P23, PB = P45 * P67;
    float2v nA = n01 * P23 + n23 * P01;
    float2v nB = n45 * P67 + n67 * P45;
    float2v P  = PA * PB;
    float2v Num = nA * PB + nB * PA;
    float2v R; R.x = frcp(P.x); R.y = frcp(P.y);
    float2v Yh = Num * R;
    return Yh.x + Yh.y;
}

// one pipeline step for slot S: consume the tile PAIR (t, t+1) held in
// zb[S], refill zb[S] with the pair 2 steps ahead, compute both tiles as
// two independent instruction streams (compiler interleaves), store, t+=W2.
template<int S>
__device__ __forceinline__ void pair_step(
    floatx4 (&zb)[2][4], int& t, int W2, int tlast, const float* zp,
    const Frag (&af)[2], const floatx4* cqg, const floatx4* nqg,
    float base, float* __restrict__ out, int m, int g)
{
    Frag bA, bB;   // consuming zb[S] waits only on its own pair; the other
    bA.d[0] = pack_bf2(zb[S][0].x, zb[S][0].y);   // slot stays in flight
    bA.d[1] = pack_bf2(zb[S][0].z, zb[S][0].w);
    bA.d[2] = pack_bf2(zb[S][1].x, zb[S][1].y);
    bA.d[3] = pack_bf2(zb[S][1].z, zb[S][1].w);
    bB.d[0] = pack_bf2(zb[S][2].x, zb[S][2].y);
    bB.d[1] = pack_bf2(zb[S][2].z, zb[S][2].w);
    bB.d[2] = pack_bf2(zb[S][3].x, zb[S][3].y);
    bB.d[3] = pack_bf2(zb[S][3].z, zb[S][3].w);

    {   // refill: keeps ~4KB outstanding per wave at all times
        int ta = t + 2 * W2; if (ta > tlast) ta = tlast;   // benign dup
        int tb = ta + 1;     if (tb > tlast) tb = tlast;
        const float* qa = zp + (size_t)ta * 512;
        const float* qb = zp + (size_t)tb * 512;
        zb[S][0] = *(const floatx4*)qa;
        zb[S][1] = *(const floatx4*)(qa + 4);
        zb[S][2] = *(const floatx4*)qb;
        zb[S][3] = *(const floatx4*)(qb + 4);
    }

    // laundered per-step index: fresh LDS broadcast reads (shared by the
    // pair) so constant tables never become resident VGPRs
    int zz = 0;
    asm volatile("" : "+v"(zz));
    const floatx4* cq = cqg + zz;
    const floatx4* nq = nqg + zz;

    float yA = 0.0f, yB = 0.0f;
    #pragma unroll
    for (int h = 0; h < 2; ++h) {
        union { floatx16 v; floatx4 q[4]; } C;
        C.q[0] = cq[h * 4 + 0]; C.q[1] = cq[h * 4 + 1];
        C.q[2] = cq[h * 4 + 2]; C.q[3] = cq[h * 4 + 3];
        // two independent MFMAs (same A, same C, different B):
        // B's MFMA latency overlaps A's tanh tree (trans pipe)
        floatx16 aA = __builtin_amdgcn_mfma_f32_32x32x16_bf16(
            af[h].v, bA.v, C.v, 0, 0, 0);
        floatx16 aB = __builtin_amdgcn_mfma_f32_32x32x16_bf16(
            af[h].v, bB.v, C.v, 0, 0, 0);

        floatx4 NQ0 = nq[h * 4 + 0], NQ1 = nq[h * 4 + 1];
        floatx4 NQ2 = nq[h * 4 + 2], NQ3 = nq[h * 4 + 3];

        // two independent tanh trees; compiler interleaves them
        yA += half_tanh(aA, NQ0, NQ1, NQ2, NQ3);
        yB += half_tanh(aB, NQ0, NQ1, NQ2, NQ3);
    }

    float oA = __shfl_xor(yA, 32, 64);
    float oB = __shfl_xor(yB, 32, 64);
    if (g == 0) {
        int tb = t + 1; if (tb > tlast) tb = tlast;  // dup store: same value
        out[(size_t)t  * 32 + m] = base + yA + oA;
        out[(size_t)tb * 32 + m] = base + yB + oB;
    }
    t += W2;
}

// y[b] = a0 + sum_k bk[k] * tanh(ck[k,:].z[b,:] + dk[k])
//
// D = mfma_32x32x16_bf16(A=s*ck, B=z, C=s*dk) -> D[node][row] = s*(dot+dk),
// s = 2*log2(e); col(lane&31)=batch row, node=(reg&3)+8*(reg>>2)+4*(lane>>5).
// tanh(t) = 1 - 2/(exp2(s*t)+1); 8-way shared denominator per half.
//
// R15 = R14's ILP experiment run VALIDLY. R14's counters exposed the bug:
// VGPR_Count=48 + WRITE_SIZE=78MB (output is 8.19MB exactly) -- the
// (256,5) 102-reg cap forced the paired body (~116 regs live) to spill
// the z pipeline to scratch; the 70MB of extra HBM writes was spill
// traffic. The ILP theory (2 independent MFMA->tanh chains per wave to
// fill the ~2x stall-stretch seen in R0's 985 issue-cy/tile vs ~450
// static) was never actually measured. Changes vs R14, ONLY residency
// arithmetic:
//  - __launch_bounds__(256,4): 128-reg budget, body fits, NO spill.
//  - grid cap 1024 = 4 blocks/CU x 256 CU co-resident at 4 waves/SIMD
//    (full static residency, no persistent-grid tail); at B=2M each wave
//    runs exactly 8 pair-steps = 16 tiles, preamble amortized 16x.
// Spill tells for the post-mortem: WRITE_SIZE must be 8192KB exactly,
// VGPR_Count 110-128. If clean and still ~78us -> structural plateau,
// declare ceiling next round.
__global__ __launch_bounds__(256, 4) void mave_kernel(
    const float* __restrict__ z,
    const float* __restrict__ a0,
    const float* __restrict__ bk,
    const float* __restrict__ ck,
    const float* __restrict__ dk,
    float* __restrict__ out,
    int ntiles)
{
    const int lane = threadIdx.x & 63;
    const int m    = lane & 31;
    const int g    = lane >> 5;
    const int widx = threadIdx.x >> 6;
    const float S  = 2.885390081777927f;  // 2*log2(e)

    // per-WAVE table copies: no cross-wave sharing -> no __syncthreads
    __shared__ __align__(16) float   cinitL[4][2][2][16];  // [wave][g][h][reg]
    __shared__ __align__(16) float2v nbL[4][2][2][8];      // [wave][g][h][j]

    const int W   = (int)(gridDim.x << 2);   // total waves
    const int W2  = W * 2;                   // tiles per step (pairs)
    const int wid = (int)(blockIdx.x * 4 + widx);
    const int t0  = wid * 2;
    if (t0 >= ntiles) return;
    const int tlast = ntiles - 1;
    const int iters = (tlast - t0) / W2 + 1;

    // ---- loads, oldest first: ck (A fragments) ----
    const float* c0 = ck + m * 16 + g * 8;
    floatx4 ckv0 = *(const floatx4*)c0;
    floatx4 ckv1 = *(const floatx4*)(c0 + 4);
    floatx4 ckv2 = *(const floatx4*)(c0 + 512);
    floatx4 ckv3 = *(const floatx4*)(c0 + 516);

    // ---- table sources (per-lane gathers; tiny, L1/L2-hot) ----
    const int tl = lane;
    const int gg = tl >> 5, hh = (tl >> 4) & 1, rr = tl & 15;
    const int nc = (rr & 3) + 8 * (rr >> 2) + 4 * gg + 32 * hh;
    float dkv = dk[nc];
    float bkt = bk[tl];
    const int g2 = tl >> 4, h2 = (tl >> 3) & 1, j2 = tl & 7;
    const int nl = (j2 & 3) + 8 * (j2 >> 2) + 4 * g2 + 32 * h2;
    float bnl = 0.0f, bnh = 0.0f;
    if (tl < 32) { bnl = bk[nl]; bnh = bk[nl + 16]; }   // exec-masked
    float a0v = a0[0];

    // ---- z pipeline: 2 slots, each a tile PAIR (youngest loads) ----
    const float* zp = z + (size_t)m * 16 + g * 8;
    floatx4 zb[2][4];
    #pragma unroll
    for (int s = 0; s < 2; ++s) {
        int ta = t0 + s * W2; if (ta > tlast) ta = tlast;   // benign dup
        int tb = ta + 1;      if (tb > tlast) tb = tlast;
        const float* qa = zp + (size_t)ta * 512;
        const float* qb = zp + (size_t)tb * 512;
        zb[s][0] = *(const floatx4*)qa;
        zb[s][1] = *(const floatx4*)(qa + 4);
        zb[s][2] = *(const floatx4*)qb;
        zb[s][3] = *(const floatx4*)(qb + 4);
    }

    // ---- consume ck (wait covers only ck; z stays in flight) ----
    Frag af[2];
    #pragma unroll
    for (int e = 0; e < 4; ++e) {
        af[0].s[e]     = f2bf(ckv0[e] * S);
        af[0].s[e + 4] = f2bf(ckv1[e] * S);
        af[1].s[e]     = f2bf(ckv2[e] * S);
        af[1].s[e + 4] = f2bf(ckv3[e] * S);
    }

    // ---- per-wave tables; same-wave RAW ordered by lgkmcnt only ----
    cinitL[widx][gg][hh][rr] = S * dkv;
    if (tl < 32) {
        float2v nb; nb.x = -2.0f * bnl; nb.y = -2.0f * bnh;
        nbL[widx][g2][h2][j2] = nb;
    }
    float bv = bkt;
    #pragma unroll
    for (int d = 1; d < 64; d <<= 1) bv += __shfl_xor(bv, d, 64);
    const float base = a0v + bv;   // all lanes hold it

    const floatx4* cqg = (const floatx4*)&cinitL[widx][g][0][0];  // 8 quads
    const floatx4* nqg = (const floatx4*)&nbL[widx][g][0][0];     // 8 quads

    // ---- persistent rolling loop: 2 tiles/step, slots alternate ----
    int t   = t0;
    int rem = iters;
    for (;;) {
        pair_step<0>(zb, t, W2, tlast, zp, af, cqg, nqg, base, out, m, g);
        if (--rem == 0) break;
        pair_step<1>(zb, t, W2, tlast, zp, af, cqg, nqg, base, out, m, g);
        if (--rem == 0) break;
    }
}

extern "C" void kernel_launch(void* const* d_in, const int* in_sizes, int n_in,
                              void* d_out, int out_size, void* d_ws, size_t ws_size,
                              hipStream_t stream) {
    const float* z  = (const float*)d_in[0];
    const float* a0 = (const float*)d_in[1];
    const float* bk = (const float*)d_in[2];
    const float* ck = (const float*)d_in[3];
    const float* dk = (const float*)d_in[4];
    float* out = (float*)d_out;

    const int B      = in_sizes[0] / 16;       // z is [B,16]
    const int ntiles = B / 32;                 // 32 batch rows per wave-tile

    // persistent, residency-exact at 4 waves/SIMD: 4 blocks/CU x 256 CU
    // = 1024 blocks (4 waves each, 2 tiles/step); whole grid co-resident
    int blocks = (ntiles + 7) / 8;
    if (blocks > 1024) blocks = 1024;
    hipLaunchKernelGGL(mave_kernel, dim3(blocks), dim3(256), 0, stream,
                       z, a0, bk, ck, dk, out, ntiles);
}

// Round 7
// 201.825 us; speedup vs baseline: 1.0718x; 1.0031x over previous
//
#include <hip/hip_runtime.h>
#include <stdint.h>

typedef __attribute__((ext_vector_type(8)))  short  short8;
typedef __attribute__((ext_vector_type(8)))  __bf16 bf16x8;
typedef __attribute__((ext_vector_type(16))) float  floatx16;
typedef __attribute__((ext_vector_type(4)))  float  floatx4;
typedef __attribute__((ext_vector_type(2)))  float  float2v;
typedef __attribute__((ext_vector_type(4)))  uint32_t uint4v;

union Frag { short8 s; bf16x8 v; uint4v d; };
union FU   { float f; uint32_t u; };

// round-to-nearest-even f32 -> bf16 (setup only)
__device__ __forceinline__ short f2bf(float f) {
    FU x; x.f = f;
    uint32_t r = x.u + 0x7fffu + ((x.u >> 16) & 1u);
    return (short)(r >> 16);
}

// pack two f32 -> bf16x2 dword, round-half-up: 2 adds + 1 v_perm
__device__ __forceinline__ uint32_t pack_bf2(float lo, float hi) {
    FU a, b; a.f = lo; b.f = hi;
    return __builtin_amdgcn_perm(b.u + 0x8000u, a.u + 0x8000u, 0x07060302u);
}

__device__ __forceinline__ float fexp2(float x) { return __builtin_amdgcn_exp2f(x); }
__device__ __forceinline__ float frcp(float x)  { return __builtin_amdgcn_rcpf(x); }

// T = exp2(min(arg,15)) + 1 for the pair (acc[j], acc[j+8]).
// No lower clamp: exp2 underflow -> 0 -> T=1 is the exact limit.
// Upper clamp 15 keeps the 8-way product <= 2^121 (no overflow);
// tanh error at the clamp ~6e-5, far under tolerance.
__device__ __forceinline__ float2v tpair(float a, float b) {
    float2v t;
    t.x = fexp2(fminf(a, 15.0f));
    t.y = fexp2(fminf(b, 15.0f));
    return t + 1.0f;
}

// one half (32 nodes) tanh-sum given the MFMA acc and the shared N quads
__device__ __forceinline__ float half_tanh(
    const floatx16& acc,
    const floatx4& NQ0, const floatx4& NQ1,
    const floatx4& NQ2, const floatx4& NQ3)
{
    union { floatx4 q; float2v p[2]; } N0, N1, N2, N3;
    N0.q = NQ0; N1.q = NQ1; N2.q = NQ2; N3.q = NQ3;

    float2v T0 = tpair(acc[0], acc[8]);
    float2v T1 = tpair(acc[1], acc[9]);
    float2v P01 = T0 * T1;
    float2v n01 = N0.p[0] * T1 + N0.p[1] * T0;
    float2v T2 = tpair(acc[2], acc[10]);
    float2v T3 = tpair(acc[3], acc[11]);
    float2v P23 = T2 * T3;
    float2v n23 = N1.p[0] * T3 + N1.p[1] * T2;
    float2v T4 = tpair(acc[4], acc[12]);
    float2v T5 = tpair(acc[5], acc[13]);
    float2v P45 = T4 * T5;
    float2v n45 = N2.p[0] * T5 + N2.p[1] * T4;
    float2v T6 = tpair(acc[6], acc[14]);
    float2v T7 = tpair(acc[7], acc[15]);
    float2v P67 = T6 * T7;
    float2v n67 = N3.p[0] * T7 + N3.p[1] * T6;

    float2v PA = P01 * P23, PB = P45 * P67;
    float2v nA = n01 * P23 + n23 * P01;
    float2v nB = n45 * P67 + n67 * P45;
    float2v P  = PA * PB;
    float2v Num = nA * PB + nB * PA;
    float2v R; R.x = frcp(P.x); R.y = frcp(P.y);
    float2v Yh = Num * R;
    return Yh.x + Yh.y;
}

// one pipeline step for slot S: consume the tile PAIR (t, t+1) held in
// zb[S], refill zb[S] with the pair 2 steps ahead, compute both tiles as
// two independent instruction streams (compiler interleaves), store, t+=W2.
template<int S>
__device__ __forceinline__ void pair_step(
    floatx4 (&zb)[2][4], int& t, int W2, int tlast, const float* zp,
    const Frag (&af)[2], const floatx4* cqg, const floatx4* nqg,
    float base, float* __restrict__ out, int m, int g)
{
    Frag bA, bB;   // consuming zb[S] waits only on its own pair; the other
    bA.d[0] = pack_bf2(zb[S][0].x, zb[S][0].y);   // slot stays in flight
    bA.d[1] = pack_bf2(zb[S][0].z, zb[S][0].w);
    bA.d[2] = pack_bf2(zb[S][1].x, zb[S][1].y);
    bA.d[3] = pack_bf2(zb[S][1].z, zb[S][1].w);
    bB.d[0] = pack_bf2(zb[S][2].x, zb[S][2].y);
    bB.d[1] = pack_bf2(zb[S][2].z, zb[S][2].w);
    bB.d[2] = pack_bf2(zb[S][3].x, zb[S][3].y);
    bB.d[3] = pack_bf2(zb[S][3].z, zb[S][3].w);

    {   // refill: keeps ~4KB outstanding per wave at all times
        int ta = t + 2 * W2; if (ta > tlast) ta = tlast;   // benign dup
        int tb = ta + 1;     if (tb > tlast) tb = tlast;
        const float* qa = zp + (size_t)ta * 512;
        const float* qb = zp + (size_t)tb * 512;
        zb[S][0] = *(const floatx4*)qa;
        zb[S][1] = *(const floatx4*)(qa + 4);
        zb[S][2] = *(const floatx4*)qb;
        zb[S][3] = *(const floatx4*)(qb + 4);
    }

    // laundered per-step index: fresh LDS broadcast reads (shared by the
    // pair) so constant tables never become resident VGPRs
    int zz = 0;
    asm volatile("" : "+v"(zz));
    const floatx4* cq = cqg + zz;
    const floatx4* nq = nqg + zz;

    float yA = 0.0f, yB = 0.0f;
    #pragma unroll
    for (int h = 0; h < 2; ++h) {
        union { floatx16 v; floatx4 q[4]; } C;
        C.q[0] = cq[h * 4 + 0]; C.q[1] = cq[h * 4 + 1];
        C.q[2] = cq[h * 4 + 2]; C.q[3] = cq[h * 4 + 3];
        // two independent MFMAs (same A, same C, different B):
        // B's MFMA latency overlaps A's tanh tree (trans pipe)
        floatx16 aA = __builtin_amdgcn_mfma_f32_32x32x16_bf16(
            af[h].v, bA.v, C.v, 0, 0, 0);
        floatx16 aB = __builtin_amdgcn_mfma_f32_32x32x16_bf16(
            af[h].v, bB.v, C.v, 0, 0, 0);

        floatx4 NQ0 = nq[h * 4 + 0], NQ1 = nq[h * 4 + 1];
        floatx4 NQ2 = nq[h * 4 + 2], NQ3 = nq[h * 4 + 3];

        // two independent tanh trees; compiler interleaves them
        yA += half_tanh(aA, NQ0, NQ1, NQ2, NQ3);
        yB += half_tanh(aB, NQ0, NQ1, NQ2, NQ3);
    }

    float oA = __shfl_xor(yA, 32, 64);
    float oB = __shfl_xor(yB, 32, 64);
    if (g == 0) {
        int tb = t + 1; if (tb > tlast) tb = tlast;  // dup store: same value
        out[(size_t)t  * 32 + m] = base + yA + oA;
        out[(size_t)tb * 32 + m] = base + yB + oB;
    }
    t += W2;
}

// y[b] = a0 + sum_k bk[k] * tanh(ck[k,:].z[b,:] + dk[k])
//
// D = mfma_32x32x16_bf16(A=s*ck, B=z, C=s*dk) -> D[node][row] = s*(dot+dk),
// s = 2*log2(e); col(lane&31)=batch row, node=(reg&3)+8*(reg>>2)+4*(lane>>5).
// tanh(t) = 1 - 2/(exp2(s*t)+1); 8-way shared denominator per half.
//
// R16 = R15 + PAGE-PRIME. Seven structurally distinct designs (occupancy
// 4->7 w/SIMD, lifetime 2->16 tiles, ILP 1->2 chains, depth 2->4, LDS vs
// reg constants, persistent vs one-shot) all plateau at ~76-83us cold,
// while every per-wave latency model predicts 10-15us: the stall is in
// shared state the kernel body doesn't control. Last differentiated
// mechanism: ADDRESS-TRANSLATION churn. The harness's 536MB re-poison
// walks ~131K distinct 4KB pages between iterations; mave then
// first-touches z's 32768 pages, each a page-walk serialized behind
// demand-load chains (~2 concurrent walks/wave). Walk cost is per-PAGE,
// dependency-serialized, and insensitive to occupancy/ILP/pipelining --
// matching the plateau; the fill is immune because it re-touches the
// same buffer (PTEs stay resident); warm=33us vs cold=78us matches.
// Falsifier: 32 lanes/block each load 4B from a distinct z page (1024
// blocks x 32 = all 32768 pages) -> ~32K concurrent walks at t=0
// saturate the XCD walkers in parallel; main loop runs on a warm TLB.
// Sink placed after the preamble so the prime wait overlaps table build.
// Null result (bench 196-205) kills the theory -> declare ceiling.
__global__ __launch_bounds__(256, 4) void mave_kernel(
    const float* __restrict__ z,
    const float* __restrict__ a0,
    const float* __restrict__ bk,
    const float* __restrict__ ck,
    const float* __restrict__ dk,
    float* __restrict__ out,
    int ntiles)
{
    const int lane = threadIdx.x & 63;
    const int m    = lane & 31;
    const int g    = lane >> 5;
    const int widx = threadIdx.x >> 6;
    const float S  = 2.885390081777927f;  // 2*log2(e)

    // per-WAVE table copies: no cross-wave sharing -> no __syncthreads
    __shared__ __align__(16) float   cinitL[4][2][2][16];  // [wave][g][h][reg]
    __shared__ __align__(16) float2v nbL[4][2][2][8];      // [wave][g][h][j]

    // ---- PAGE-PRIME: issue FIRST (oldest loads device-wide). 32 lanes of
    // wave 0 of each block touch 32 distinct 4KB pages of z -> 32 parallel
    // page-walks per block, all blocks at t=0. Value consumed by an asm
    // sink AFTER the preamble (wait overlaps table build). ----
    float prime = 0.0f;
    {
        const size_t zfloats = (size_t)ntiles * 512;
        if (threadIdx.x < 32) {
            size_t pg = ((size_t)blockIdx.x * 32 + threadIdx.x) * 1024;
            if (pg < zfloats) prime = z[pg];
        }
    }

    const int W   = (int)(gridDim.x << 2);   // total waves
    const int W2  = W * 2;                   // tiles per step (pairs)
    const int wid = (int)(blockIdx.x * 4 + widx);
    const int t0  = wid * 2;
    if (t0 >= ntiles) return;
    const int tlast = ntiles - 1;
    const int iters = (tlast - t0) / W2 + 1;

    // ---- loads: ck (A fragments) ----
    const float* c0 = ck + m * 16 + g * 8;
    floatx4 ckv0 = *(const floatx4*)c0;
    floatx4 ckv1 = *(const floatx4*)(c0 + 4);
    floatx4 ckv2 = *(const floatx4*)(c0 + 512);
    floatx4 ckv3 = *(const floatx4*)(c0 + 516);

    // ---- table sources (per-lane gathers; tiny, L1/L2-hot) ----
    const int tl = lane;
    const int gg = tl >> 5, hh = (tl >> 4) & 1, rr = tl & 15;
    const int nc = (rr & 3) + 8 * (rr >> 2) + 4 * gg + 32 * hh;
    float dkv = dk[nc];
    float bkt = bk[tl];
    const int g2 = tl >> 4, h2 = (tl >> 3) & 1, j2 = tl & 7;
    const int nl = (j2 & 3) + 8 * (j2 >> 2) + 4 * g2 + 32 * h2;
    float bnl = 0.0f, bnh = 0.0f;
    if (tl < 32) { bnl = bk[nl]; bnh = bk[nl + 16]; }   // exec-masked
    float a0v = a0[0];

    // ---- z pipeline: 2 slots, each a tile PAIR (youngest loads) ----
    const float* zp = z + (size_t)m * 16 + g * 8;
    floatx4 zb[2][4];
    #pragma unroll
    for (int s = 0; s < 2; ++s) {
        int ta = t0 + s * W2; if (ta > tlast) ta = tlast;   // benign dup
        int tb = ta + 1;      if (tb > tlast) tb = tlast;
        const float* qa = zp + (size_t)ta * 512;
        const float* qb = zp + (size_t)tb * 512;
        zb[s][0] = *(const floatx4*)qa;
        zb[s][1] = *(const floatx4*)(qa + 4);
        zb[s][2] = *(const floatx4*)qb;
        zb[s][3] = *(const floatx4*)(qb + 4);
    }

    // ---- consume ck (wait covers only ck+prime; z stays in flight) ----
    Frag af[2];
    #pragma unroll
    for (int e = 0; e < 4; ++e) {
        af[0].s[e]     = f2bf(ckv0[e] * S);
        af[0].s[e + 4] = f2bf(ckv1[e] * S);
        af[1].s[e]     = f2bf(ckv2[e] * S);
        af[1].s[e + 4] = f2bf(ckv3[e] * S);
    }

    // ---- per-wave tables; same-wave RAW ordered by lgkmcnt only ----
    cinitL[widx][gg][hh][rr] = S * dkv;
    if (tl < 32) {
        float2v nb; nb.x = -2.0f * bnl; nb.y = -2.0f * bnh;
        nbL[widx][g2][h2][j2] = nb;
    }
    float bv = bkt;
    #pragma unroll
    for (int d = 1; d < 64; d <<= 1) bv += __shfl_xor(bv, d, 64);
    const float base = a0v + bv;   // all lanes hold it

    // prime sink: forces the prime load to be kept, wait lands HERE
    // (after preamble), not at issue point
    asm volatile("" :: "v"(prime));

    const floatx4* cqg = (const floatx4*)&cinitL[widx][g][0][0];  // 8 quads
    const floatx4* nqg = (const floatx4*)&nbL[widx][g][0][0];     // 8 quads

    // ---- persistent rolling loop: 2 tiles/step, slots alternate ----
    int t   = t0;
    int rem = iters;
    for (;;) {
        pair_step<0>(zb, t, W2, tlast, zp, af, cqg, nqg, base, out, m, g);
        if (--rem == 0) break;
        pair_step<1>(zb, t, W2, tlast, zp, af, cqg, nqg, base, out, m, g);
        if (--rem == 0) break;
    }
}

extern "C" void kernel_launch(void* const* d_in, const int* in_sizes, int n_in,
                              void* d_out, int out_size, void* d_ws, size_t ws_size,
                              hipStream_t stream) {
    const float* z  = (const float*)d_in[0];
    const float* a0 = (const float*)d_in[1];
    const float* bk = (const float*)d_in[2];
    const float* ck = (const float*)d_in[3];
    const float* dk = (const float*)d_in[4];
    float* out = (float*)d_out;

    const int B      = in_sizes[0] / 16;       // z is [B,16]
    const int ntiles = B / 32;                 // 32 batch rows per wave-tile

    // persistent, residency-exact at 4 waves/SIMD: 4 blocks/CU x 256 CU
    // = 1024 blocks (4 waves each, 2 tiles/step); whole grid co-resident.
    // 1024 blocks x 32 = all 32768 z pages primed.
    int blocks = (ntiles + 7) / 8;
    if (blocks > 1024) blocks = 1024;
    hipLaunchKernelGGL(mave_kernel, dim3(blocks), dim3(256), 0, stream,
                       z, a0, bk, ck, dk, out, ntiles);
}

// Round 8
// 200.786 us; speedup vs baseline: 1.0774x; 1.0052x over previous
//
#include <hip/hip_runtime.h>
#include <stdint.h>

typedef __attribute__((ext_vector_type(8)))  short  short8;
typedef __attribute__((ext_vector_type(8)))  __bf16 bf16x8;
typedef __attribute__((ext_vector_type(16))) float  floatx16;
typedef __attribute__((ext_vector_type(4)))  float  floatx4;
typedef __attribute__((ext_vector_type(2)))  float  float2v;
typedef __attribute__((ext_vector_type(4)))  uint32_t uint4v;

union Frag { short8 s; bf16x8 v; uint4v d; };
union FU   { float f; uint32_t u; };

// round-to-nearest-even f32 -> bf16 (setup only)
__device__ __forceinline__ short f2bf(float f) {
    FU x; x.f = f;
    uint32_t r = x.u + 0x7fffu + ((x.u >> 16) & 1u);
    return (short)(r >> 16);
}

// pack two f32 -> bf16x2 dword, round-half-up: 2 adds + 1 v_perm
__device__ __forceinline__ uint32_t pack_bf2(float lo, float hi) {
    FU a, b; a.f = lo; b.f = hi;
    return __builtin_amdgcn_perm(b.u + 0x8000u, a.u + 0x8000u, 0x07060302u);
}

__device__ __forceinline__ float fexp2(float x) { return __builtin_amdgcn_exp2f(x); }
__device__ __forceinline__ float frcp(float x)  { return __builtin_amdgcn_rcpf(x); }

// T = exp2(min(arg,15)) + 1 for the pair (acc[j], acc[j+8]).
// No lower clamp: exp2 underflow -> 0 -> T=1 is the exact limit.
// Upper clamp 15 keeps the 8-way product <= 2^121; tanh err ~6e-5.
__device__ __forceinline__ float2v tpair(float a, float b) {
    float2v t;
    t.x = fexp2(fminf(a, 15.0f));
    t.y = fexp2(fminf(b, 15.0f));
    return t + 1.0f;
}

// direct global->LDS (compiler never auto-emits; dest = uniform base + lane*16)
typedef const __attribute__((address_space(1))) void* gas_t;
typedef __attribute__((address_space(3)))       void* las_t;
__device__ __forceinline__ void gload16(const void* g, void* l) {
    __builtin_amdgcn_global_load_lds((gas_t)g, (las_t)l, 16, 0, 0);
}

// one half (32 nodes) tanh-sum; nb = 8 register pairs (same math as R15's
// verified half_tanh, constants in VGPRs instead of LDS)
__device__ __forceinline__ float half_tanh_reg(const floatx16& acc, const float2v* nb)
{
    float2v T0 = tpair(acc[0], acc[8]);
    float2v T1 = tpair(acc[1], acc[9]);
    float2v P01 = T0 * T1;
    float2v n01 = nb[0] * T1 + nb[1] * T0;
    float2v T2 = tpair(acc[2], acc[10]);
    float2v T3 = tpair(acc[3], acc[11]);
    float2v P23 = T2 * T3;
    float2v n23 = nb[2] * T3 + nb[3] * T2;
    float2v T4 = tpair(acc[4], acc[12]);
    float2v T5 = tpair(acc[5], acc[13]);
    float2v P45 = T4 * T5;
    float2v n45 = nb[4] * T5 + nb[5] * T4;
    float2v T6 = tpair(acc[6], acc[14]);
    float2v T7 = tpair(acc[7], acc[15]);
    float2v P67 = T6 * T7;
    float2v n67 = nb[6] * T7 + nb[7] * T6;

    float2v PA = P01 * P23, PB = P45 * P67;
    float2v nA = n01 * P23 + n23 * P01;
    float2v nB = n45 * P67 + n67 * P45;
    float2v P  = PA * PB;
    float2v Num = nA * PB + nB * PA;
    float2v R; R.x = frcp(P.x); R.y = frcp(P.y);
    float2v Yh = Num * R;
    return Yh.x + Yh.y;
}

// y[b] = a0 + sum_k bk[k] * tanh(ck[k,:].z[b,:] + dk[k])
//
// D = mfma_32x32x16_bf16(A=s*ck, B=z, C=s*dk) -> D[node][row] = s*(dot+dk),
// s = 2*log2(e); col(lane&31)=batch row, node=(reg&3)+8*(reg>>2)+4*(lane>>5).
// tanh(t) = 1 - 2/(exp2(s*t)+1); 8-way shared denominator per half.
//
// R17 theory (decouple loads from registers): every prior design staged z
// into VGPRs, so outstanding-bytes/wave was coupled to register deps and
// COMPILER-placed vmcnt waits; measured effective in-flight ~1.3KB/CU vs
// 4-8KB designed -> those waits drain far more than the source model says.
// This kernel owns the waits:
//  - z staged via global_load_lds into a per-wave 4-slot LDS ring (2KB
//    tile slots, 8KB/wave, 32KB/block, NO barrier, no cross-wave sharing).
//  - staging is a pre-permuted gather: lane l fetches its OWN fragment
//    bytes (zp + t*512 + j*4), so linear LDS write => conflict-free
//    linear ds_read_b128 (lane*16) on consumption. No swizzle.
//  - hand-counted s_waitcnt: vmcnt(6) peel / vmcnt(9) steady (2 loads +
//    1 store per iter; slot-S loads always have >=9 younger VMEM ops).
//    Never 0 in the loop. sched_barrier(0) after each wait (rule #18).
//  - register constants (cinit/nb/af ~72 regs); __launch_bounds__(256,3)
//    = 170-reg budget -> guaranteed no spill (R14 lesson). 768 blocks =
//    3 blocks/CU co-resident, 12 waves/CU, ~21 tiles/wave persistent.
// Steady in-flight: 12 waves x ~6KB = 72KB/CU vs 1.3KB measured before.
// Tells: LDS_Block_Size=32768, WRITE_SIZE=8192KB exactly (no spill).
__global__ __launch_bounds__(256, 3) void mave_kernel(
    const float* __restrict__ z,
    const float* __restrict__ a0,
    const float* __restrict__ bk,
    const float* __restrict__ ck,
    const float* __restrict__ dk,
    float* __restrict__ out,
    int ntiles)
{
    const int lane = threadIdx.x & 63;
    const int m    = lane & 31;
    const int g    = lane >> 5;
    const int widx = threadIdx.x >> 6;
    const float S  = 2.885390081777927f;  // 2*log2(e)

    // per-wave 4-slot ring: [wave][slot][2KB]; written ONLY by gload16
    __shared__ __align__(16) char ring[4][4][2048];

    const int W   = (int)(gridDim.x << 2);   // total waves
    const int wid = (int)(blockIdx.x * 4 + widx);
    if (wid >= ntiles) return;
    const int tlast = ntiles - 1;
    const int iters = (tlast - wid) / W + 1;

    // ---- 1. ck vector loads (oldest), 2. A-fragments ----
    const float* c0 = ck + m * 16 + g * 8;
    floatx4 ckv0 = *(const floatx4*)c0;
    floatx4 ckv1 = *(const floatx4*)(c0 + 4);
    floatx4 ckv2 = *(const floatx4*)(c0 + 512);
    floatx4 ckv3 = *(const floatx4*)(c0 + 516);
    Frag af[2];
    #pragma unroll
    for (int e = 0; e < 4; ++e) {
        af[0].s[e]     = f2bf(ckv0[e] * S);
        af[0].s[e + 4] = f2bf(ckv1[e] * S);
        af[1].s[e]     = f2bf(ckv2[e] * S);
        af[1].s[e + 4] = f2bf(ckv3[e] * S);
    }

    // ---- 3. constant gathers + 4. register tables (all BEFORE ring
    //      issue, so their waits can't drain ring loads) ----
    floatx16 cinit[2];
    #pragma unroll
    for (int r = 0; r < 16; ++r) {
        int n = (r & 3) + 8 * (r >> 2) + 4 * g;
        cinit[0][r] = S * dk[n];
        cinit[1][r] = S * dk[n + 32];
    }
    float2v nb[2][8];
    #pragma unroll
    for (int h = 0; h < 2; ++h)
        #pragma unroll
        for (int j = 0; j < 8; ++j) {
            int nl = (j & 3) + 8 * (j >> 2) + 4 * g + 32 * h;
            nb[h][j].x = -2.0f * bk[nl];
            nb[h][j].y = -2.0f * bk[nl + 16];
        }
    float bkt = bk[lane];
    float a0v = a0[0];

    // ---- 5. ring prologue: slots 0..3 <- tiles wid..wid+3W ----
    const float* zp = z + (size_t)m * 16 + g * 8;   // lane's fragment base
    #pragma unroll
    for (int s = 0; s < 4; ++s) {
        int ti = wid + s * W; if (ti > tlast) ti = tlast;   // benign dup
        const float* q = zp + (size_t)ti * 512;
        gload16(q,     &ring[widx][s][0]);      // j=0 chunk -> [0,1K)
        gload16(q + 4, &ring[widx][s][1024]);   // j=1 chunk -> [1K,2K)
    }

    // ---- 6. base reduce (bkt/a0v are OLDER than ring loads: the
    //      compiler's wait here leaves the ring in flight) ----
    float bv = bkt;
    #pragma unroll
    for (int d = 1; d < 64; d <<= 1) bv += __shfl_xor(bv, d, 64);
    const float base = a0v + bv;

    // one iteration: counted wait -> linear ds_read -> compute -> refill
    // issue (slack = 4 iters >> HBM latency) -> store. 2 loads + 1 store
    // per iter keeps the vmcnt arithmetic exact.
    #define STEP(SLOT, VMN)                                                   \
    do {                                                                      \
        asm volatile("s_waitcnt vmcnt(" #VMN ")" ::: "memory");               \
        __builtin_amdgcn_sched_barrier(0);                                    \
        const floatx4* sp = (const floatx4*)&ring[widx][SLOT][0];             \
        floatx4 z0 = sp[lane];        /* ds_read_b128, linear: no conflict */ \
        floatx4 z1 = sp[64 + lane];                                           \
        Frag bfr;                                                             \
        bfr.d[0] = pack_bf2(z0.x, z0.y);                                      \
        bfr.d[1] = pack_bf2(z0.z, z0.w);                                      \
        bfr.d[2] = pack_bf2(z1.x, z1.y);                                      \
        bfr.d[3] = pack_bf2(z1.z, z1.w);                                      \
        float ya = 0.0f;                                                      \
        _Pragma("unroll")                                                     \
        for (int h = 0; h < 2; ++h) {                                         \
            floatx16 acc = __builtin_amdgcn_mfma_f32_32x32x16_bf16(           \
                af[h].v, bfr.v, cinit[h], 0, 0, 0);                           \
            ya += half_tanh_reg(acc, nb[h]);                                  \
        }                                                                     \
        {   /* refill slot for tile t+4W (clamped: benign dup) */             \
            int tn = t + 4 * W; if (tn > tlast) tn = tlast;                   \
            const float* q = zp + (size_t)tn * 512;                           \
            gload16(q,     &ring[widx][SLOT][0]);                             \
            gload16(q + 4, &ring[widx][SLOT][1024]);                          \
        }                                                                     \
        float ov = __shfl_xor(ya, 32, 64);                                    \
        if (g == 0) out[(size_t)t * 32 + m] = base + ya + ov;                 \
        t += W;                                                               \
    } while (0)

    int t = wid, rem = iters;
    // peel: vmcnt(6) is <= the younger-op count at each of the first 4
    // iters (6,7,8,9) -> current slot always complete, ring stays hot
    STEP(0, 6); if (--rem == 0) return;
    STEP(1, 6); if (--rem == 0) return;
    STEP(2, 6); if (--rem == 0) return;
    STEP(3, 6); if (--rem == 0) return;
    // steady: younger = 10 (3 slots x 2 loads + 4 stores... counted: 9
    // leaves 3 tiles of lookahead + stores in flight; never drains to 0)
    for (;;) {
        STEP(0, 9); if (--rem == 0) break;
        STEP(1, 9); if (--rem == 0) break;
        STEP(2, 9); if (--rem == 0) break;
        STEP(3, 9); if (--rem == 0) break;
    }
    #undef STEP
}

extern "C" void kernel_launch(void* const* d_in, const int* in_sizes, int n_in,
                              void* d_out, int out_size, void* d_ws, size_t ws_size,
                              hipStream_t stream) {
    const float* z  = (const float*)d_in[0];
    const float* a0 = (const float*)d_in[1];
    const float* bk = (const float*)d_in[2];
    const float* ck = (const float*)d_in[3];
    const float* dk = (const float*)d_in[4];
    float* out = (float*)d_out;

    const int B      = in_sizes[0] / 16;       // z is [B,16]
    const int ntiles = B / 32;                 // 32 batch rows per wave-tile

    // persistent, residency-exact: 3 blocks/CU x 256 CU = 768 blocks
    // (32KB LDS + <=170 VGPR each), 12 waves/CU, ~21 tiles/wave at B=2M
    int blocks = (ntiles + 15) / 16;
    if (blocks > 768) blocks = 768;
    hipLaunchKernelGGL(mave_kernel, dim3(blocks), dim3(256), 0, stream,
                       z, a0, bk, ck, dk, out, ntiles);
}